// Round 1
// baseline (233.278 us; speedup 1.0000x reference)
//
#include <hip/hip_runtime.h>
#include <math.h>

// Problem constants (from reference)
#define GAMMA 0.98f
#define LBDA  0.93f
#define GL    (GAMMA * LBDA)   // gamma*lambda
constexpr int B  = 2048;
constexpr int T  = 1024;
constexpr int NT = B * T;      // 2,097,152

// ---------------------------------------------------------------------------
// log_pi = x[a] - logsumexp(x[0..5])
// ---------------------------------------------------------------------------
__device__ __forceinline__ float logpi(float x0, float x1, float x2,
                                       float x3, float x4, float x5, int a) {
    float m = fmaxf(fmaxf(fmaxf(x0, x1), fmaxf(x2, x3)), fmaxf(x4, x5));
    float s = __expf(x0 - m) + __expf(x1 - m) + __expf(x2 - m) +
              __expf(x3 - m) + __expf(x4 - m) + __expf(x5 - m);
    float lse = m + __logf(s);
    float r = x0;
    r = (a == 1) ? x1 : r;
    r = (a == 2) ? x2 : r;
    r = (a == 3) ? x3 : r;
    r = (a == 4) ? x4 : r;
    r = (a == 5) ? x5 : r;
    return r - lse;
}

// ---------------------------------------------------------------------------
// Kernel 1: elementwise log-softmax gather. Thread i handles elements 2i,2i+1.
// Writes ratio r=exp(lp-lpo) to rbuf, accumulates entropy sum (sum of lp).
// 2 elements -> 12 logits floats = 3 aligned float4 per array.
// ---------------------------------------------------------------------------
__global__ __launch_bounds__(256) void k_elem(
        const float4* __restrict__ lg, const float4* __restrict__ lgo,
        const int2* __restrict__ act, float2* __restrict__ rbuf,
        float* __restrict__ acc) {
    int i = blockIdx.x * 256 + threadIdx.x;      // i < NT/2 (exact grid)
    float4 A0 = lg[3 * i], A1 = lg[3 * i + 1], A2 = lg[3 * i + 2];
    float4 B0 = lgo[3 * i], B1 = lgo[3 * i + 1], B2 = lgo[3 * i + 2];
    int2 aa = act[i];

    float lp0  = logpi(A0.x, A0.y, A0.z, A0.w, A1.x, A1.y, aa.x);
    float lp1  = logpi(A1.z, A1.w, A2.x, A2.y, A2.z, A2.w, aa.y);
    float lpo0 = logpi(B0.x, B0.y, B0.z, B0.w, B1.x, B1.y, aa.x);
    float lpo1 = logpi(B1.z, B1.w, B2.x, B2.y, B2.z, B2.w, aa.y);

    rbuf[i] = make_float2(__expf(lp0 - lpo0), __expf(lp1 - lpo1));

    // block-reduce entropy sum
    float es = lp0 + lp1;
    #pragma unroll
    for (int d = 32; d; d >>= 1) es += __shfl_xor(es, d);
    __shared__ float sm[4];
    int lane = threadIdx.x & 63;
    if (lane == 0) sm[threadIdx.x >> 6] = es;
    __syncthreads();
    if (threadIdx.x == 0) atomicAdd(acc + 0, sm[0] + sm[1] + sm[2] + sm[3]);
}

// ---------------------------------------------------------------------------
// Kernel 2: one block (256 threads) per batch row. Thread j owns timesteps
// t = 4j..4j+3 (coalesced float4 loads). Both reverse recurrences
//   Rs[t] = base1[t] + c1[t]*Rs[t+1]   (returns)
//   A[t]  = base2[t] + c2[t]*A[t+1]    (GAE)
// are solved exactly via affine-map suffix composition:
// per-thread local map -> wave Hillis-Steele suffix scan -> 4-wave LDS fixup
// -> replay 4 steps with exact carry, accumulating value/ppo loss sums.
// ---------------------------------------------------------------------------
__global__ __launch_bounds__(256) void k_scan(
        const float4* __restrict__ rw4, const float4* __restrict__ vl4,
        const int4* __restrict__ dn4, const float4* __restrict__ rr4,
        float* __restrict__ acc) {
    int j = threadIdx.x;
    int base = blockIdx.x * 256 + j;
    float4 rw = rw4[base], vl = vl4[base], rr = rr4[base];
    int4 dn = dn4[base];

    __shared__ float sv[256];
    __shared__ float wa1[4], wb1[4], wa2[4], wb2[4];
    __shared__ float red[8];

    sv[j] = vl.x;                 // values at t = 4j
    __syncthreads();
    float vnext = (j < 255) ? sv[j + 1] : 0.0f;   // values[4j+4] (unused j=255)

    float rwk[4] = {rw.x, rw.y, rw.z, rw.w};
    float vk[5]  = {vl.x, vl.y, vl.z, vl.w, vnext};
    int   dk[4]  = {dn.x, dn.y, dn.z, dn.w};

    float b1[4], c1[4], b2[4], c2[4];
    #pragma unroll
    for (int k = 0; k < 4; ++k) {
        bool d = dk[k] != 0;
        c1[k] = d ? 0.0f : GAMMA;
        b1[k] = rwk[k];
        c2[k] = d ? 0.0f : GL;
        b2[k] = rwk[k] + (d ? 0.0f : GAMMA * vk[k + 1]) - vk[k];  // td error
    }
    if (j == 255) {  // t = T-1 special: Rs[T-1] = d ? r : v ; A[T-1] = 0
        b1[3] = dk[3] ? rwk[3] : vk[3];
        c1[3] = 0.0f;
        b2[3] = 0.0f;
        c2[3] = 0.0f;
    }

    // local suffix composition over k = 3..0: map carry-in(at t=4j+4) -> R[4j]
    float a1 = 1.0f, bb1 = 0.0f, a2 = 1.0f, bb2 = 0.0f;
    #pragma unroll
    for (int k = 3; k >= 0; --k) {
        bb1 = b1[k] + c1[k] * bb1;  a1 = c1[k] * a1;
        bb2 = b2[k] + c2[k] * bb2;  a2 = c2[k] * a2;
    }

    // wave-level inclusive SUFFIX scan (composition L(R(x)): a=aL*aR, b=aL*bR+bL)
    int lane = j & 63, wv = j >> 6;
    #pragma unroll
    for (int d = 1; d < 64; d <<= 1) {
        float an1 = __shfl_down(a1, d), bn1 = __shfl_down(bb1, d);
        float an2 = __shfl_down(a2, d), bn2 = __shfl_down(bb2, d);
        if (lane + d < 64) {
            bb1 = a1 * bn1 + bb1;  a1 = a1 * an1;
            bb2 = a2 * bn2 + bb2;  a2 = a2 * an2;
        }
    }
    if (lane == 0) { wa1[wv] = a1; wb1[wv] = bb1; wa2[wv] = a2; wb2[wv] = bb2; }
    // neighbor's suffix map S_{j+1} (before overwrite; shuffles need no sync)
    float a1s = __shfl_down(a1, 1), b1s = __shfl_down(bb1, 1);
    float a2s = __shfl_down(a2, 1), b2s = __shfl_down(bb2, 1);
    __syncthreads();

    // carry entering this wave's high end (apply later waves' maps to init=0)
    float x1 = 0.0f, x2 = 0.0f;
    for (int w2 = 3; w2 > wv; --w2) {
        x1 = wa1[w2] * x1 + wb1[w2];
        x2 = wa2[w2] * x2 + wb2[w2];
    }
    // carry entering this thread (value at t = 4j+4)
    float cin1 = (lane == 63) ? x1 : (a1s * x1 + b1s);
    float cin2 = (lane == 63) ? x2 : (a2s * x2 + b2s);

    // replay the 4 steps with exact carries, accumulate losses
    float rrk[4] = {rr.x, rr.y, rr.z, rr.w};
    float vsum = 0.0f, psum = 0.0f;
    float R = cin1, A = cin2;
    #pragma unroll
    for (int k = 3; k >= 0; --k) {
        R = b1[k] + c1[k] * R;
        float dv = R - vk[k];
        vsum += dv * dv;
        A = b2[k] + c2[k] * A;
        if (4 * j + k < T - 1) {
            // faithful torch clip(min=0.8,max=0.2) -> r_clipped == 0.2
            psum += fminf(rrk[k] * A, 0.2f * A);
        }
    }

    #pragma unroll
    for (int d = 32; d; d >>= 1) {
        vsum += __shfl_xor(vsum, d);
        psum += __shfl_xor(psum, d);
    }
    if (lane == 0) { red[wv] = vsum; red[4 + wv] = psum; }
    __syncthreads();
    if (j == 0) {
        atomicAdd(acc + 1, red[0] + red[1] + red[2] + red[3]);
        atomicAdd(acc + 2, red[4] + red[5] + red[6] + red[7]);
    }
}

// ---------------------------------------------------------------------------
// Kernel 3: finalize the three means.
// ---------------------------------------------------------------------------
__global__ void k_fin(const float* __restrict__ acc, float* __restrict__ out) {
    out[0] = -acc[2] / (float)(B * (T - 1));   // ppo_loss
    out[1] =  acc[1] / (float)(B * T);         // value_loss
    out[2] = -acc[0] / (float)(B * T);         // entropy_loss
}

// ---------------------------------------------------------------------------
extern "C" void kernel_launch(void* const* d_in, const int* in_sizes, int n_in,
                              void* d_out, int out_size, void* d_ws, size_t ws_size,
                              hipStream_t stream) {
    const float* rewards    = (const float*)d_in[0];
    const float* values     = (const float*)d_in[1];
    const float* logits     = (const float*)d_in[2];
    const float* logits_old = (const float*)d_in[3];
    const int*   dones      = (const int*)d_in[4];
    const int*   actions    = (const int*)d_in[5];

    float* acc  = (float*)d_ws;        // acc[0]=entropy sum, [1]=value sum, [2]=ppo sum
    float* rbuf = acc + 4;             // ratio buffer, NT floats (8 MB), 16B aligned

    hipMemsetAsync(d_ws, 0, 4 * sizeof(float), stream);

    k_elem<<<NT / 2 / 256, 256, 0, stream>>>(
        (const float4*)logits, (const float4*)logits_old,
        (const int2*)actions, (float2*)rbuf, acc);

    k_scan<<<B, 256, 0, stream>>>(
        (const float4*)rewards, (const float4*)values,
        (const int4*)dones, (const float4*)rbuf, acc);

    k_fin<<<1, 1, 0, stream>>>(acc, (float*)d_out);
}